// Round 9
// baseline (671.208 us; speedup 1.0000x reference)
//
#include <hip/hip_runtime.h>
#include <hip/hip_bf16.h>
#include <math.h>

#define NV 20000
#define NE 320000
#define CSR_PAD 8

typedef __attribute__((ext_vector_type(8))) short bf16x8;
typedef __attribute__((ext_vector_type(4))) float f32x4;

static __device__ __forceinline__ ushort f2b(float f) {
  __hip_bfloat16 h = __float2bfloat16(f);
  return *reinterpret_cast<ushort*>(&h);
}
static __device__ __forceinline__ float b2f(ushort u) {
  union { ushort s[2]; float f; } c;
  c.s[0] = 0; c.s[1] = u;
  return c.f;
}

// DPP wave-64 sum: 6 VALU adds; lane 63 holds total, broadcast via readlane.
static __device__ __forceinline__ float wave_sum64(float x) {
  x += __int_as_float(__builtin_amdgcn_update_dpp(0, __float_as_int(x), 0x111, 0xF, 0xF, true));
  x += __int_as_float(__builtin_amdgcn_update_dpp(0, __float_as_int(x), 0x112, 0xF, 0xF, true));
  x += __int_as_float(__builtin_amdgcn_update_dpp(0, __float_as_int(x), 0x114, 0xF, 0xF, true));
  x += __int_as_float(__builtin_amdgcn_update_dpp(0, __float_as_int(x), 0x118, 0xF, 0xF, true));
  x += __int_as_float(__builtin_amdgcn_update_dpp(0, __float_as_int(x), 0x142, 0xA, 0xF, true));
  x += __int_as_float(__builtin_amdgcn_update_dpp(0, __float_as_int(x), 0x143, 0xC, 0xF, true));
  return __int_as_float(__builtin_amdgcn_readlane(__float_as_int(x), 63));
}

// dot of 16 bf16 channels (packed in 2 uint4, lo=ch2j, hi=ch2j+1) with f32 Wc
static __device__ __forceinline__ float dot16b(const uint4* __restrict__ E2,
                                               const float* __restrict__ Wc) {
  const unsigned* u = (const unsigned*)E2;
  float s = 0.f;
#pragma unroll
  for (int j = 0; j < 8; ++j) {
    float lo = __uint_as_float(u[j] << 16);
    float hi = __uint_as_float(u[j] & 0xffff0000u);
    s = fmaf(lo, Wc[2 * j], s);
    s = fmaf(hi, Wc[2 * j + 1], s);
  }
  return s;
}

// ---------------- batched prep: CSR hist + ea colsum (y<3), W casts (y==3), proj (y==4) ----------------
struct CJob { const float* src; ushort* dst; int K, M; };
struct PrepArgs {
  const int* ei[3];
  const float* ea[3];
  int* counts[3];
  float* easum[3];
  CJob jobs[9];
  const float *x, *Wp, *bp, *gp, *bep;
  ushort* h0;
};

__global__ __launch_bounds__(256) void prep_kernel(PrepArgs a) {
  const int y = blockIdx.y, t = threadIdx.x;
  if (y < 3) {
    // ea column sums: 256 blocks, float4 loads, one shared reduce -> 16 atomics/block
    if (blockIdx.x < 256) {
      const float4* ea4 = (const float4*)a.ea[y];
      const int cg = t & 3;
      int r = blockIdx.x * 64 + (t >> 2);
      const int rstride = 256 * 64;
      float4 s = make_float4(0.f, 0.f, 0.f, 0.f);
      for (; r < NE; r += rstride) {
        float4 v = ea4[(size_t)r * 4 + cg];
        s.x += v.x; s.y += v.y; s.z += v.z; s.w += v.w;
      }
      __shared__ float4 red4[256];
      red4[t] = s;
      __syncthreads();
      if (t < 4) {
        float4 tot = make_float4(0.f, 0.f, 0.f, 0.f);
        for (int j = t; j < 256; j += 4) {
          float4 v = red4[j];
          tot.x += v.x; tot.y += v.y; tot.z += v.z; tot.w += v.w;
        }
        atomicAdd(&a.easum[y][t * 4 + 0], tot.x);
        atomicAdd(&a.easum[y][t * 4 + 1], tot.y);
        atomicAdd(&a.easum[y][t * 4 + 2], tot.z);
        atomicAdd(&a.easum[y][t * 4 + 3], tot.w);
      }
    }
    // dst histogram over real edges only (self loops handled analytically in agg)
    int i = blockIdx.x * 256 + t;
    if (i < NE) atomicAdd(&a.counts[y][a.ei[y][NE + i]], 1);
  } else if (y == 3) {
    // weight transpose-casts
#pragma unroll
    for (int j = 0; j < 9; ++j) {
      CJob jb = a.jobs[j];
      const int total = jb.M * jb.K;
      for (int i = blockIdx.x * 256 + t; i < total; i += gridDim.x * 256) {
        int m = i / jb.K, k = i - m * jb.K;
        jb.dst[i] = f2b(jb.src[(size_t)k * jb.M + m]);
      }
    }
  } else {
    // proj: h0 = gelu(LN(x@Wp + bp)) (grid-stride over rows)
    int wid = t >> 6, lane = t & 63;
    for (int row = blockIdx.x * 4 + wid; row < NV; row += gridDim.x * 4) {
      float xv = a.x[(size_t)row * 64 + lane];
      float acc = a.bp[lane];
#pragma unroll
      for (int k = 0; k < 64; ++k) {
        float v = __shfl(xv, k, 64);
        acc = fmaf(v, a.Wp[k * 64 + lane], acc);
      }
      float s1 = wave_sum64(acc), s2 = wave_sum64(acc * acc);
      float mean = s1 * (1.0f / 64.0f);
      float var  = s2 * (1.0f / 64.0f) - mean * mean;
      float yv = (acc - mean) * rsqrtf(var + 1e-5f) * a.gp[lane] + a.bep[lane];
      float gel = 0.5f * yv * (1.0f + erff(yv * 0.70710678118654752f));
      a.h0[(size_t)row * 64 + lane] = f2b(gel);
    }
  }
}

// ---------------- batched scan: blockIdx.x = layer ----------------
__global__ __launch_bounds__(1024) void scan_kernel(
    int* __restrict__ countsA, int* __restrict__ cursorA)
{
  int* counts = countsA + blockIdx.x * (NV + 1);
  int* cursor = cursorA + blockIdx.x * NV;
  __shared__ int ws[16];
  __shared__ int wexcl[17];
  const int t = threadIdx.x, lane = t & 63, wid = t >> 6;
  const int base = t * 20;
  int v[20];
  int tot = 0;
#pragma unroll
  for (int j = 0; j < 20; ++j) {
    int i = base + j;
    v[j] = (i < NV) ? counts[i] : 0;
    tot += v[j];
  }
  int x = tot;
#pragma unroll
  for (int o = 1; o < 64; o <<= 1) {
    int yy = __shfl_up(x, o, 64);
    if (lane >= o) x += yy;
  }
  if (lane == 63) ws[wid] = x;
  __syncthreads();
  if (t == 0) {
    int r = 0;
#pragma unroll
    for (int j = 0; j < 16; ++j) { wexcl[j] = r; r += ws[j]; }
    wexcl[16] = r;
  }
  __syncthreads();
  int run = wexcl[wid] + (x - tot);
#pragma unroll
  for (int j = 0; j < 20; ++j) {
    int i = base + j;
    if (i < NV) { counts[i] = run; cursor[i] = run; }
    run += v[j];
  }
  if (t == 0) counts[NV] = wexcl[16];
}

// ---------------- batched scatter: src-offset CSR + ea rows reordered to CSR order (bf16) ----------------
// Turning the agg's ea access from random-by-edge-id (HBM-latency bound; 20.5 MB
// working set thrashes the 4 MB per-XCD L2 -> 111 MB FETCH in r8) into a
// sequential-by-position stream.
struct ScatArgs { const int* ei[3]; const float* ea[3]; int* cursor[3];
                  unsigned* csr[3]; ushort* eab[3]; int HC[3]; };
__global__ __launch_bounds__(256) void scatter_kernel(ScatArgs a) {
  const int l = blockIdx.y;
  int i = blockIdx.x * 256 + threadIdx.x;
  if (i >= NE + CSR_PAD) return;
  if (i >= NE) {  // prefetch pad
    a.csr[l][i] = 0u;
    uint4 z = make_uint4(0, 0, 0, 0);
    *(uint4*)(a.eab[l] + (size_t)i * 16) = z;
    *(uint4*)(a.eab[l] + (size_t)i * 16 + 8) = z;
    return;
  }
  int dst = a.ei[l][NE + i], src = a.ei[l][i];
  int pos = atomicAdd(&a.cursor[l][dst], 1);
  a.csr[l][pos] = (unsigned)(src * a.HC[l]);
  const float4* er = (const float4*)(a.ea[l] + (size_t)i * 16);  // sequential read
  float4 q0 = er[0], q1 = er[1], q2 = er[2], q3 = er[3];
  uint4 w0, w1;
  w0.x = (unsigned)f2b(q0.x) | ((unsigned)f2b(q0.y) << 16);
  w0.y = (unsigned)f2b(q0.z) | ((unsigned)f2b(q0.w) << 16);
  w0.z = (unsigned)f2b(q1.x) | ((unsigned)f2b(q1.y) << 16);
  w0.w = (unsigned)f2b(q1.z) | ((unsigned)f2b(q1.w) << 16);
  w1.x = (unsigned)f2b(q2.x) | ((unsigned)f2b(q2.y) << 16);
  w1.y = (unsigned)f2b(q2.z) | ((unsigned)f2b(q2.w) << 16);
  w1.z = (unsigned)f2b(q3.x) | ((unsigned)f2b(q3.y) << 16);
  w1.w = (unsigned)f2b(q3.z) | ((unsigned)f2b(q3.w) << 16);
  *(uint4*)(a.eab[l] + (size_t)pos * 16) = w0;
  *(uint4*)(a.eab[l] + (size_t)pos * 16 + 8) = w1;
}

// ---------------- fused per-layer GEMM: [xl | xr | res] = A @ [Wl|Wr|Wsk] + bias ----------------
__global__ __launch_bounds__(256) void gemm_fused(
    const ushort* __restrict__ A, const ushort* __restrict__ WT,
    const float* __restrict__ b0, const float* __restrict__ b1,
    const float* __restrict__ b2,
    ushort* __restrict__ O0, ushort* __restrict__ O1, float* __restrict__ O2,
    int N, int K, int M1, int M2, int Mtot)
{
  __shared__ ushort As[128][40];
  __shared__ ushort Bs[64][40];
  const int t = threadIdx.x, wave = t >> 6, lane = t & 63;
  const int row0 = blockIdx.y * 128, col0 = blockIdx.x * 64;
  const int m_ = lane & 15, q = lane >> 4;
  f32x4 acc[2][4];
#pragma unroll
  for (int i = 0; i < 2; ++i)
#pragma unroll
    for (int j = 0; j < 4; ++j) acc[i][j] = (f32x4){0.f, 0.f, 0.f, 0.f};

  const int ar = t >> 1, ac = (t & 1) * 16;
  const int br = t >> 2, bcol = (t & 3) * 8;
  const ushort* Ap = A + (size_t)(row0 + ar) * K + ac;
  const ushort* Bp = WT + (size_t)(col0 + br) * K + bcol;
  const bool a_ok = (row0 + ar) < N;

  for (int k0 = 0; k0 < K; k0 += 32) {
    uint4 av0 = make_uint4(0, 0, 0, 0), av1 = make_uint4(0, 0, 0, 0);
    if (a_ok) { av0 = *(const uint4*)(Ap + k0); av1 = *(const uint4*)(Ap + k0 + 8); }
    uint4 bv = *(const uint4*)(Bp + k0);
    *(uint4*)&As[ar][ac] = av0;
    *(uint4*)&As[ar][ac + 8] = av1;
    *(uint4*)&Bs[br][bcol] = bv;
    __syncthreads();
    bf16x8 a0 = *(const bf16x8*)&As[wave * 32 + m_][q * 8];
    bf16x8 a1 = *(const bf16x8*)&As[wave * 32 + 16 + m_][q * 8];
#pragma unroll
    for (int cf = 0; cf < 4; ++cf) {
      bf16x8 b = *(const bf16x8*)&Bs[cf * 16 + m_][q * 8];
      acc[0][cf] = __builtin_amdgcn_mfma_f32_16x16x32_bf16(a0, b, acc[0][cf], 0, 0, 0);
      acc[1][cf] = __builtin_amdgcn_mfma_f32_16x16x32_bf16(a1, b, acc[1][cf], 0, 0, 0);
    }
    __syncthreads();
  }

  const float* bias; int base, mode, Wd;
  if (col0 < M1)      { bias = b0; base = 0;  mode = 0; Wd = M1; }
  else if (col0 < M2) { bias = b1; base = M1; mode = 1; Wd = M2 - M1; }
  else                { bias = b2; base = M2; mode = 2; Wd = Mtot - M2; }

#pragma unroll
  for (int rf = 0; rf < 2; ++rf) {
#pragma unroll
    for (int cf = 0; cf < 4; ++cf) {
      int col = col0 + cf * 16 + m_ - base;
      float bb = bias[col];
#pragma unroll
      for (int r = 0; r < 4; ++r) {
        int row = row0 + wave * 32 + rf * 16 + q * 4 + r;
        if (row < N) {
          float v = acc[rf][cf][r] + bb;
          if (mode == 0)      O0[(size_t)row * Wd + col] = f2b(v);
          else if (mode == 1) O1[(size_t)row * Wd + col] = f2b(v);
          else                O2[(size_t)row * Wd + col] = v;
        }
      }
    }
  }
}

// ---------------- fused GATv2: score + softmax + aggregate + LN + gelu + res ----------------
// H=4: one block (4 waves) per node. H=1: one wave per node, 4 nodes/block.
// Self-loop analytic; CSR = src offsets only; ea rows pre-reordered (sequential
// stream, prefetched one iteration ahead into registers); exp2 w/ folded log2e.
template <int H>
__global__ __launch_bounds__(256, 4) void fused_agg_kernel(
    const ushort* __restrict__ eab, const float* __restrict__ easum,
    const float* __restrict__ We,
    const ushort* __restrict__ xl, const ushort* __restrict__ xr,
    const float* __restrict__ att, const float* __restrict__ bc,
    const float* __restrict__ g, const float* __restrict__ be,
    const float* __restrict__ res,
    const int* __restrict__ offs, const unsigned* __restrict__ csr,
    float* __restrict__ houtf, ushort* __restrict__ houtb, int E)
{
  const int HC = H * 64;
  const int t = threadIdx.x, lane = t & 63, wave = t >> 6;
  const int n = (H == 1) ? blockIdx.x * 4 + wave : blockIdx.x;
  const int c = (H == 1) ? lane : t;

  const float xr_t = b2f(xr[(size_t)n * HC + c]);
  const float att_t = att[c] * 1.4426950408889634f;  // fold log2(e)
  float Wc[16];
#pragma unroll
  for (int k = 0; k < 16; ++k) Wc[k] = We[k * HC + c];
  float eself = 0.f;
#pragma unroll
  for (int k = 0; k < 16; ++k) eself = fmaf(easum[k], Wc[k], eself);
  eself *= 1.0f / (float)E;

  // self-loop contribution (analytic)
  const float xln = b2f(xl[(size_t)n * HC + c]);
  float vs = xln + xr_t + eself;
  vs = vs > 0.f ? vs : 0.2f * vs;
  const float wself = exp2f(wave_sum64(vs * att_t));
  float acc = wself * xln, denom = wself;

  const int beg = __builtin_amdgcn_readfirstlane(offs[n]);
  const int end = __builtin_amdgcn_readfirstlane(offs[n + 1]);

  unsigned P[4];
  uint4 EA[4][2];
#pragma unroll
  for (int k = 0; k < 4; ++k) {
    P[k] = csr[beg + k];
    const uint4* ep = (const uint4*)(eab + (size_t)(beg + k) * 16);
    EA[k][0] = ep[0]; EA[k][1] = ep[1];
  }

  for (int idx = beg; idx < end; idx += 4) {
    unsigned Q[4];
    uint4 EB[4][2];
#pragma unroll
    for (int k = 0; k < 4; ++k) {
      Q[k] = csr[idx + 4 + k];
      const uint4* ep = (const uint4*)(eab + (size_t)(idx + 4 + k) * 16);
      EB[k][0] = ep[0]; EB[k][1] = ep[1];
    }

    float xls[4], ee[4], wv[4];
#pragma unroll
    for (int k = 0; k < 4; ++k) {
      const unsigned so = __builtin_amdgcn_readfirstlane(P[k]);  // src*HC
      xls[k] = b2f(xl[so + c]);
      ee[k] = dot16b(EA[k], Wc);
    }
#pragma unroll
    for (int k = 0; k < 4; ++k) {
      float v = xls[k] + xr_t + ee[k];
      v = v > 0.f ? v : 0.2f * v;  // leaky_relu(0.2)
      float S = wave_sum64(v * att_t);
      wv[k] = (idx + k < end) ? exp2f(S) : 0.f;
    }
#pragma unroll
    for (int k = 0; k < 4; ++k) { acc = fmaf(wv[k], xls[k], acc); denom += wv[k]; }
#pragma unroll
    for (int k = 0; k < 4; ++k) { P[k] = Q[k]; EA[k][0] = EB[k][0]; EA[k][1] = EB[k][1]; }
  }

  float out = acc / (denom + 1e-16f) + bc[c];

  // LayerNorm across HC channels
  float s1 = wave_sum64(out), s2 = wave_sum64(out * out);
  if (H > 1) {
    __shared__ float r1s[4], r2s[4];
    if (lane == 0) { r1s[wave] = s1; r2s[wave] = s2; }
    __syncthreads();
    s1 = 0.f; s2 = 0.f;
#pragma unroll
    for (int j = 0; j < H; ++j) { s1 += r1s[j]; s2 += r2s[j]; }
  }
  float mean = s1 / (float)HC;
  float var  = s2 / (float)HC - mean * mean;
  float y = (out - mean) * rsqrtf(var + 1e-5f) * g[c] + be[c];
  float gel = 0.5f * y * (1.0f + erff(y * 0.70710678118654752f));
  float o = gel + res[(size_t)n * HC + c];
  if (houtf) houtf[(size_t)n * HC + c] = o;
  if (houtb) houtb[(size_t)n * HC + c] = f2b(o);
}

// ---------------- host launch ----------------
extern "C" void kernel_launch(void* const* d_in, const int* in_sizes, int n_in,
                              void* d_out, int out_size, void* d_ws, size_t ws_size,
                              hipStream_t stream)
{
  const float* x = (const float*)d_in[0];
  const int*   ei[3] = {(const int*)d_in[1], (const int*)d_in[3], (const int*)d_in[5]};
  const float* ea[3] = {(const float*)d_in[2], (const float*)d_in[4], (const float*)d_in[6]};
  auto in = [&](int i) { return (const float*)d_in[i]; };
  // per-layer base 11 + 11*i: Wl, bl, Wr, br, We, att, bc, g, be, Wsk, bsk

  const int ic[3] = {64, 256, 256}, hc[3] = {256, 256, 64}, oc[3] = {256, 256, 64};
  const int CSRN = NE + CSR_PAD;

  // ---- workspace layout (~100 MB) ----
  char* w = (char*)d_ws;
  size_t off = 0;
  auto alloc = [&](size_t bytes) { void* p = w + off; off = (off + bytes + 511) & ~(size_t)511; return p; };
  ushort* B1   = (ushort*)alloc((size_t)NV * 256 * 2);  // xl (bf16)
  ushort* B2   = (ushort*)alloc((size_t)NV * 256 * 2);  // xr (bf16)
  float*  B3   = (float*)alloc((size_t)NV * 256 * 4);   // res (f32)
  ushort* h0bf = (ushort*)alloc((size_t)NV * 64 * 2);
  ushort* h1bf = (ushort*)alloc((size_t)NV * 256 * 2);
  ushort* h2bf = (ushort*)alloc((size_t)NV * 256 * 2);
  ushort* Wcat[3];
  for (int i = 0; i < 3; ++i)
    Wcat[i] = (ushort*)alloc((size_t)(2 * hc[i] + oc[i]) * ic[i] * 2);
  float*    easumA  = (float*)alloc(3 * 64);                  // 3 x 16 floats
  int*      countsA = (int*)alloc((size_t)3 * (NV + 1) * 4);  // adjacent for one memset
  int*      cursorA = (int*)alloc((size_t)3 * NV * 4);
  unsigned* csrA    = (unsigned*)alloc((size_t)3 * CSRN * 4);
  ushort*   eabA    = (ushort*)alloc((size_t)3 * CSRN * 16 * 2);  // reordered bf16 ea

  // ---- single memset: easums + counts ----
  hipMemsetAsync(easumA, 0, 512 + (size_t)3 * (NV + 1) * 4, stream);

  // ---- batched prep: CSR hist + colsum (x3), weight casts, proj ----
  PrepArgs pa;
  for (int i = 0; i < 3; ++i) {
    pa.ei[i] = ei[i];
    pa.ea[i] = ea[i];
    pa.counts[i] = countsA + i * (NV + 1);
    pa.easum[i] = easumA + i * 16;
    pa.jobs[i * 3 + 0] = {in(11 + 11 * i), Wcat[i],                             ic[i], hc[i]};
    pa.jobs[i * 3 + 1] = {in(13 + 11 * i), Wcat[i] + (size_t)hc[i] * ic[i],     ic[i], hc[i]};
    pa.jobs[i * 3 + 2] = {in(20 + 11 * i), Wcat[i] + (size_t)2 * hc[i] * ic[i], ic[i], oc[i]};
  }
  pa.x = x; pa.Wp = in(7); pa.bp = in(8); pa.gp = in(9); pa.bep = in(10); pa.h0 = h0bf;
  prep_kernel<<<dim3(1344, 5), 256, 0, stream>>>(pa);

  // ---- batched scan + scatter (scatter also reorders ea -> bf16 CSR order) ----
  scan_kernel<<<3, 1024, 0, stream>>>(countsA, cursorA);
  ScatArgs sa;
  for (int i = 0; i < 3; ++i) {
    sa.ei[i] = ei[i];
    sa.ea[i] = ea[i];
    sa.cursor[i] = cursorA + i * NV;
    sa.csr[i] = csrA + (size_t)i * CSRN;
    sa.eab[i] = eabA + (size_t)i * CSRN * 16;
    sa.HC[i] = hc[i];
  }
  scatter_kernel<<<dim3((NE + CSR_PAD + 255) / 256, 3), 256, 0, stream>>>(sa);

  // ---- per-layer: fused GEMM + fused aggregate ----
  const ushort* hin[3] = {h0bf, h1bf, h2bf};
  ushort* hout_bf[3] = {h1bf, h2bf, nullptr};
  for (int i = 0; i < 3; ++i) {
    int K = ic[i], HCm = hc[i], OC = oc[i];
    int Mtot = 2 * HCm + OC;
    gemm_fused<<<dim3(Mtot / 64, (NV + 127) / 128), 256, 0, stream>>>(
        hin[i], Wcat[i], in(12 + 11 * i), in(14 + 11 * i), in(21 + 11 * i),
        B1, B2, B3, NV, K, HCm, 2 * HCm, Mtot);
    const int* offs = countsA + i * (NV + 1);
    const unsigned* csr = csrA + (size_t)i * CSRN;
    const ushort* eab = eabA + (size_t)i * CSRN * 16;
    const float* easum = easumA + i * 16;
    if (i < 2) {
      fused_agg_kernel<4><<<NV, 256, 0, stream>>>(
          eab, easum, in(15 + 11 * i), B1, B2, in(16 + 11 * i),
          in(17 + 11 * i), in(18 + 11 * i), in(19 + 11 * i), B3,
          offs, csr, nullptr, hout_bf[i], NE);
    } else {
      fused_agg_kernel<1><<<(NV + 3) / 4, 256, 0, stream>>>(
          eab, easum, in(15 + 11 * i), B1, B2, in(16 + 11 * i),
          in(17 + 11 * i), in(18 + 11 * i), in(19 + 11 * i), B3,
          offs, csr, (float*)d_out, nullptr, NE);
    }
  }
}

// Round 10
// 636.587 us; speedup vs baseline: 1.0544x; 1.0544x over previous
//
#include <hip/hip_runtime.h>
#include <hip/hip_bf16.h>
#include <math.h>

#define NV 20000
#define NE 320000
#define CSR_PAD 8

typedef __attribute__((ext_vector_type(8))) short bf16x8;
typedef __attribute__((ext_vector_type(4))) float f32x4;
typedef __attribute__((ext_vector_type(2))) _Float16 h2;

static __device__ __forceinline__ ushort f2b(float f) {
  __hip_bfloat16 h = __float2bfloat16(f);
  return *reinterpret_cast<ushort*>(&h);
}
static __device__ __forceinline__ float b2f(ushort u) {
  union { ushort s[2]; float f; } c;
  c.s[0] = 0; c.s[1] = u;
  return c.f;
}
static __device__ __forceinline__ ushort f2h(float f) {
  _Float16 h = (_Float16)f;
  return *reinterpret_cast<ushort*>(&h);
}

// DPP wave-64 sum: 6 VALU adds; lane 63 holds total, broadcast via readlane.
static __device__ __forceinline__ float wave_sum64(float x) {
  x += __int_as_float(__builtin_amdgcn_update_dpp(0, __float_as_int(x), 0x111, 0xF, 0xF, true));
  x += __int_as_float(__builtin_amdgcn_update_dpp(0, __float_as_int(x), 0x112, 0xF, 0xF, true));
  x += __int_as_float(__builtin_amdgcn_update_dpp(0, __float_as_int(x), 0x114, 0xF, 0xF, true));
  x += __int_as_float(__builtin_amdgcn_update_dpp(0, __float_as_int(x), 0x118, 0xF, 0xF, true));
  x += __int_as_float(__builtin_amdgcn_update_dpp(0, __float_as_int(x), 0x142, 0xA, 0xF, true));
  x += __int_as_float(__builtin_amdgcn_update_dpp(0, __float_as_int(x), 0x143, 0xC, 0xF, true));
  return __int_as_float(__builtin_amdgcn_readlane(__float_as_int(x), 63));
}

// 16-channel dot: edge attrs as 8 packed f16 pairs vs pre-packed We pairs.
static __device__ __forceinline__ float dot16h(const uint4* __restrict__ E,
                                               const h2* __restrict__ Wch) {
#if __has_builtin(__builtin_amdgcn_fdot2)
  const h2* e = (const h2*)E;
  float s = 0.f;
#pragma unroll
  for (int j = 0; j < 8; ++j) s = __builtin_amdgcn_fdot2(e[j], Wch[j], s, false);
  return s;
#else
  const unsigned* u = (const unsigned*)E;
  float s = 0.f;
#pragma unroll
  for (int j = 0; j < 8; ++j) {
    union { unsigned v; h2 h; } cv; cv.v = u[j];
    s = fmaf((float)cv.h[0], (float)Wch[j][0], s);
    s = fmaf((float)cv.h[1], (float)Wch[j][1], s);
  }
  return s;
#endif
}

// ---------------- batched prep: CSR hist + ea colsum (y<3), W casts (y==3), proj (y==4) ----------------
struct CJob { const float* src; ushort* dst; int K, M; };
struct PrepArgs {
  const int* ei[3];
  const float* ea[3];
  int* counts[3];
  float* easum[3];
  CJob jobs[9];
  const float *x, *Wp, *bp, *gp, *bep;
  ushort* h0;
};

__global__ __launch_bounds__(256) void prep_kernel(PrepArgs a) {
  const int y = blockIdx.y, t = threadIdx.x;
  if (y < 3) {
    // ea column sums: 256 blocks, float4 loads, one shared reduce -> 16 atomics/block
    if (blockIdx.x < 256) {
      const float4* ea4 = (const float4*)a.ea[y];
      const int cg = t & 3;
      int r = blockIdx.x * 64 + (t >> 2);
      const int rstride = 256 * 64;
      float4 s = make_float4(0.f, 0.f, 0.f, 0.f);
      for (; r < NE; r += rstride) {
        float4 v = ea4[(size_t)r * 4 + cg];
        s.x += v.x; s.y += v.y; s.z += v.z; s.w += v.w;
      }
      __shared__ float4 red4[256];
      red4[t] = s;
      __syncthreads();
      if (t < 4) {
        float4 tot = make_float4(0.f, 0.f, 0.f, 0.f);
        for (int j = t; j < 256; j += 4) {
          float4 v = red4[j];
          tot.x += v.x; tot.y += v.y; tot.z += v.z; tot.w += v.w;
        }
        atomicAdd(&a.easum[y][t * 4 + 0], tot.x);
        atomicAdd(&a.easum[y][t * 4 + 1], tot.y);
        atomicAdd(&a.easum[y][t * 4 + 2], tot.z);
        atomicAdd(&a.easum[y][t * 4 + 3], tot.w);
      }
    }
    // dst histogram over real edges only (self loops handled analytically in agg)
    int i = blockIdx.x * 256 + t;
    if (i < NE) atomicAdd(&a.counts[y][a.ei[y][NE + i]], 1);
  } else if (y == 3) {
    // weight transpose-casts
#pragma unroll
    for (int j = 0; j < 9; ++j) {
      CJob jb = a.jobs[j];
      const int total = jb.M * jb.K;
      for (int i = blockIdx.x * 256 + t; i < total; i += gridDim.x * 256) {
        int m = i / jb.K, k = i - m * jb.K;
        jb.dst[i] = f2b(jb.src[(size_t)k * jb.M + m]);
      }
    }
  } else {
    // proj: h0 = gelu(LN(x@Wp + bp)) (grid-stride over rows)
    int wid = t >> 6, lane = t & 63;
    for (int row = blockIdx.x * 4 + wid; row < NV; row += gridDim.x * 4) {
      float xv = a.x[(size_t)row * 64 + lane];
      float acc = a.bp[lane];
#pragma unroll
      for (int k = 0; k < 64; ++k) {
        float v = __shfl(xv, k, 64);
        acc = fmaf(v, a.Wp[k * 64 + lane], acc);
      }
      float s1 = wave_sum64(acc), s2 = wave_sum64(acc * acc);
      float mean = s1 * (1.0f / 64.0f);
      float var  = s2 * (1.0f / 64.0f) - mean * mean;
      float yv = (acc - mean) * rsqrtf(var + 1e-5f) * a.gp[lane] + a.bep[lane];
      float gel = 0.5f * yv * (1.0f + erff(yv * 0.70710678118654752f));
      a.h0[(size_t)row * 64 + lane] = f2b(gel);
    }
  }
}

// ---------------- batched scan: blockIdx.x = layer ----------------
__global__ __launch_bounds__(1024) void scan_kernel(
    int* __restrict__ countsA, int* __restrict__ cursorA)
{
  int* counts = countsA + blockIdx.x * (NV + 1);
  int* cursor = cursorA + blockIdx.x * NV;
  __shared__ int ws[16];
  __shared__ int wexcl[17];
  const int t = threadIdx.x, lane = t & 63, wid = t >> 6;
  const int base = t * 20;
  int v[20];
  int tot = 0;
#pragma unroll
  for (int j = 0; j < 20; ++j) {
    int i = base + j;
    v[j] = (i < NV) ? counts[i] : 0;
    tot += v[j];
  }
  int x = tot;
#pragma unroll
  for (int o = 1; o < 64; o <<= 1) {
    int yy = __shfl_up(x, o, 64);
    if (lane >= o) x += yy;
  }
  if (lane == 63) ws[wid] = x;
  __syncthreads();
  if (t == 0) {
    int r = 0;
#pragma unroll
    for (int j = 0; j < 16; ++j) { wexcl[j] = r; r += ws[j]; }
    wexcl[16] = r;
  }
  __syncthreads();
  int run = wexcl[wid] + (x - tot);
#pragma unroll
  for (int j = 0; j < 20; ++j) {
    int i = base + j;
    if (i < NV) { counts[i] = run; cursor[i] = run; }
    run += v[j];
  }
  if (t == 0) counts[NV] = wexcl[16];
}

// ---------------- batched scatter: src-offset CSR + ea rows reordered to CSR order (f16) ----------------
struct ScatArgs { const int* ei[3]; const float* ea[3]; int* cursor[3];
                  unsigned* csr[3]; ushort* eab[3]; int HC[3]; };
__global__ __launch_bounds__(256) void scatter_kernel(ScatArgs a) {
  const int l = blockIdx.y;
  int i = blockIdx.x * 256 + threadIdx.x;
  if (i >= NE + CSR_PAD) return;
  if (i >= NE) {  // prefetch pad
    a.csr[l][i] = 0u;
    uint4 z = make_uint4(0, 0, 0, 0);
    *(uint4*)(a.eab[l] + (size_t)i * 16) = z;
    *(uint4*)(a.eab[l] + (size_t)i * 16 + 8) = z;
    return;
  }
  int dst = a.ei[l][NE + i], src = a.ei[l][i];
  int pos = atomicAdd(&a.cursor[l][dst], 1);
  a.csr[l][pos] = (unsigned)(src * a.HC[l]);
  const float4* er = (const float4*)(a.ea[l] + (size_t)i * 16);  // sequential read
  float4 q0 = er[0], q1 = er[1], q2 = er[2], q3 = er[3];
  uint4 w0, w1;
  w0.x = (unsigned)f2h(q0.x) | ((unsigned)f2h(q0.y) << 16);
  w0.y = (unsigned)f2h(q0.z) | ((unsigned)f2h(q0.w) << 16);
  w0.z = (unsigned)f2h(q1.x) | ((unsigned)f2h(q1.y) << 16);
  w0.w = (unsigned)f2h(q1.z) | ((unsigned)f2h(q1.w) << 16);
  w1.x = (unsigned)f2h(q2.x) | ((unsigned)f2h(q2.y) << 16);
  w1.y = (unsigned)f2h(q2.z) | ((unsigned)f2h(q2.w) << 16);
  w1.z = (unsigned)f2h(q3.x) | ((unsigned)f2h(q3.y) << 16);
  w1.w = (unsigned)f2h(q3.z) | ((unsigned)f2h(q3.w) << 16);
  *(uint4*)(a.eab[l] + (size_t)pos * 16) = w0;
  *(uint4*)(a.eab[l] + (size_t)pos * 16 + 8) = w1;
}

// ---------------- fused per-layer GEMM: [xl | xr | res] = A @ [Wl|Wr|Wsk] + bias ----------------
__global__ __launch_bounds__(256) void gemm_fused(
    const ushort* __restrict__ A, const ushort* __restrict__ WT,
    const float* __restrict__ b0, const float* __restrict__ b1,
    const float* __restrict__ b2,
    ushort* __restrict__ O0, ushort* __restrict__ O1, float* __restrict__ O2,
    int N, int K, int M1, int M2, int Mtot)
{
  __shared__ ushort As[128][40];
  __shared__ ushort Bs[64][40];
  const int t = threadIdx.x, wave = t >> 6, lane = t & 63;
  const int row0 = blockIdx.y * 128, col0 = blockIdx.x * 64;
  const int m_ = lane & 15, q = lane >> 4;
  f32x4 acc[2][4];
#pragma unroll
  for (int i = 0; i < 2; ++i)
#pragma unroll
    for (int j = 0; j < 4; ++j) acc[i][j] = (f32x4){0.f, 0.f, 0.f, 0.f};

  const int ar = t >> 1, ac = (t & 1) * 16;
  const int br = t >> 2, bcol = (t & 3) * 8;
  const ushort* Ap = A + (size_t)(row0 + ar) * K + ac;
  const ushort* Bp = WT + (size_t)(col0 + br) * K + bcol;
  const bool a_ok = (row0 + ar) < N;

  for (int k0 = 0; k0 < K; k0 += 32) {
    uint4 av0 = make_uint4(0, 0, 0, 0), av1 = make_uint4(0, 0, 0, 0);
    if (a_ok) { av0 = *(const uint4*)(Ap + k0); av1 = *(const uint4*)(Ap + k0 + 8); }
    uint4 bv = *(const uint4*)(Bp + k0);
    *(uint4*)&As[ar][ac] = av0;
    *(uint4*)&As[ar][ac + 8] = av1;
    *(uint4*)&Bs[br][bcol] = bv;
    __syncthreads();
    bf16x8 a0 = *(const bf16x8*)&As[wave * 32 + m_][q * 8];
    bf16x8 a1 = *(const bf16x8*)&As[wave * 32 + 16 + m_][q * 8];
#pragma unroll
    for (int cf = 0; cf < 4; ++cf) {
      bf16x8 b = *(const bf16x8*)&Bs[cf * 16 + m_][q * 8];
      acc[0][cf] = __builtin_amdgcn_mfma_f32_16x16x32_bf16(a0, b, acc[0][cf], 0, 0, 0);
      acc[1][cf] = __builtin_amdgcn_mfma_f32_16x16x32_bf16(a1, b, acc[1][cf], 0, 0, 0);
    }
    __syncthreads();
  }

  const float* bias; int base, mode, Wd;
  if (col0 < M1)      { bias = b0; base = 0;  mode = 0; Wd = M1; }
  else if (col0 < M2) { bias = b1; base = M1; mode = 1; Wd = M2 - M1; }
  else                { bias = b2; base = M2; mode = 2; Wd = Mtot - M2; }

#pragma unroll
  for (int rf = 0; rf < 2; ++rf) {
#pragma unroll
    for (int cf = 0; cf < 4; ++cf) {
      int col = col0 + cf * 16 + m_ - base;
      float bb = bias[col];
#pragma unroll
      for (int r = 0; r < 4; ++r) {
        int row = row0 + wave * 32 + rf * 16 + q * 4 + r;
        if (row < N) {
          float v = acc[rf][cf][r] + bb;
          if (mode == 0)      O0[(size_t)row * Wd + col] = f2b(v);
          else if (mode == 1) O1[(size_t)row * Wd + col] = f2b(v);
          else                O2[(size_t)row * Wd + col] = v;
        }
      }
    }
  }
}

// ---------------- fused GATv2: score + softmax + aggregate + LN + gelu + res ----------------
// H=4: one block (4 waves) per node. H=1: one wave per node, 4 nodes/block.
// Self-loop analytic; ea pre-reordered (f16, sequential); xl gather SOFTWARE-
// PIPELINED one iteration ahead (the r9 stall: xls issued+consumed in-iteration);
// ee via v_dot2_f32_f16 on packed pairs.
template <int H>
__global__ __launch_bounds__(256, 4) void fused_agg_kernel(
    const ushort* __restrict__ eab, const float* __restrict__ easum,
    const float* __restrict__ We,
    const ushort* __restrict__ xl, const ushort* __restrict__ xr,
    const float* __restrict__ att, const float* __restrict__ bc,
    const float* __restrict__ g, const float* __restrict__ be,
    const float* __restrict__ res,
    const int* __restrict__ offs, const unsigned* __restrict__ csr,
    float* __restrict__ houtf, ushort* __restrict__ houtb, int E)
{
  const int HC = H * 64;
  const int t = threadIdx.x, lane = t & 63, wave = t >> 6;
  const int n = (H == 1) ? blockIdx.x * 4 + wave : blockIdx.x;
  const int c = (H == 1) ? lane : t;

  const float xr_t = b2f(xr[(size_t)n * HC + c]);
  const float att_t = att[c] * 1.4426950408889634f;  // fold log2(e)
  float eself = 0.f;
  h2 Wch[8];
#pragma unroll
  for (int j = 0; j < 8; ++j) {
    float w0 = We[(2 * j) * HC + c], w1 = We[(2 * j + 1) * HC + c];
    eself = fmaf(easum[2 * j], w0, eself);
    eself = fmaf(easum[2 * j + 1], w1, eself);
    Wch[j] = (h2){(_Float16)w0, (_Float16)w1};
  }
  eself *= 1.0f / (float)E;

  // self-loop contribution (analytic)
  const float xln = b2f(xl[(size_t)n * HC + c]);
  float vs = xln + xr_t + eself;
  vs = vs > 0.f ? vs : 0.2f * vs;
  const float wself = exp2f(wave_sum64(vs * att_t));
  float acc = wself * xln, denom = wself;

  const int beg = __builtin_amdgcn_readfirstlane(offs[n]);
  const int end = __builtin_amdgcn_readfirstlane(offs[n + 1]);

  // prime: offsets, ea rows, AND xl values for the first 4 edges
  unsigned P[4];
  uint4 EA[4][2];
  float XL[4];
#pragma unroll
  for (int k = 0; k < 4; ++k) {
    P[k] = csr[beg + k];
    const uint4* ep = (const uint4*)(eab + (size_t)(beg + k) * 16);
    EA[k][0] = ep[0]; EA[k][1] = ep[1];
  }
#pragma unroll
  for (int k = 0; k < 4; ++k)
    XL[k] = b2f(xl[__builtin_amdgcn_readfirstlane(P[k]) + c]);

  for (int idx = beg; idx < end; idx += 4) {
    // prefetch next iteration's offsets, ea rows, xl values (issued before the
    // ~240-cyc compute below -> latency covered)
    unsigned Q[4];
    uint4 EB[4][2];
    float XLN[4];
#pragma unroll
    for (int k = 0; k < 4; ++k) Q[k] = csr[idx + 4 + k];
#pragma unroll
    for (int k = 0; k < 4; ++k) {
      const uint4* ep = (const uint4*)(eab + (size_t)(idx + 4 + k) * 16);
      EB[k][0] = ep[0]; EB[k][1] = ep[1];
    }
#pragma unroll
    for (int k = 0; k < 4; ++k)
      XLN[k] = b2f(xl[__builtin_amdgcn_readfirstlane(Q[k]) + c]);

    float wv[4];
#pragma unroll
    for (int k = 0; k < 4; ++k) {
      float ee = dot16h(EA[k], Wch);
      float v = XL[k] + xr_t + ee;
      v = v > 0.f ? v : 0.2f * v;  // leaky_relu(0.2)
      float S = wave_sum64(v * att_t);
      wv[k] = (idx + k < end) ? exp2f(S) : 0.f;
    }
#pragma unroll
    for (int k = 0; k < 4; ++k) { acc = fmaf(wv[k], XL[k], acc); denom += wv[k]; }
#pragma unroll
    for (int k = 0; k < 4; ++k) {
      P[k] = Q[k]; EA[k][0] = EB[k][0]; EA[k][1] = EB[k][1]; XL[k] = XLN[k];
    }
  }

  float out = acc / (denom + 1e-16f) + bc[c];

  // LayerNorm across HC channels
  float s1 = wave_sum64(out), s2 = wave_sum64(out * out);
  if (H > 1) {
    __shared__ float r1s[4], r2s[4];
    if (lane == 0) { r1s[wave] = s1; r2s[wave] = s2; }
    __syncthreads();
    s1 = 0.f; s2 = 0.f;
#pragma unroll
    for (int j = 0; j < H; ++j) { s1 += r1s[j]; s2 += r2s[j]; }
  }
  float mean = s1 / (float)HC;
  float var  = s2 / (float)HC - mean * mean;
  float y = (out - mean) * rsqrtf(var + 1e-5f) * g[c] + be[c];
  float gel = 0.5f * y * (1.0f + erff(y * 0.70710678118654752f));
  float o = gel + res[(size_t)n * HC + c];
  if (houtf) houtf[(size_t)n * HC + c] = o;
  if (houtb) houtb[(size_t)n * HC + c] = f2b(o);
}

// ---------------- host launch ----------------
extern "C" void kernel_launch(void* const* d_in, const int* in_sizes, int n_in,
                              void* d_out, int out_size, void* d_ws, size_t ws_size,
                              hipStream_t stream)
{
  const float* x = (const float*)d_in[0];
  const int*   ei[3] = {(const int*)d_in[1], (const int*)d_in[3], (const int*)d_in[5]};
  const float* ea[3] = {(const float*)d_in[2], (const float*)d_in[4], (const float*)d_in[6]};
  auto in = [&](int i) { return (const float*)d_in[i]; };
  // per-layer base 11 + 11*i: Wl, bl, Wr, br, We, att, bc, g, be, Wsk, bsk

  const int ic[3] = {64, 256, 256}, hc[3] = {256, 256, 64}, oc[3] = {256, 256, 64};
  const int CSRN = NE + CSR_PAD;

  // ---- workspace layout (~100 MB) ----
  char* w = (char*)d_ws;
  size_t off = 0;
  auto alloc = [&](size_t bytes) { void* p = w + off; off = (off + bytes + 511) & ~(size_t)511; return p; };
  ushort* B1   = (ushort*)alloc((size_t)NV * 256 * 2);  // xl (bf16)
  ushort* B2   = (ushort*)alloc((size_t)NV * 256 * 2);  // xr (bf16)
  float*  B3   = (float*)alloc((size_t)NV * 256 * 4);   // res (f32)
  ushort* h0bf = (ushort*)alloc((size_t)NV * 64 * 2);
  ushort* h1bf = (ushort*)alloc((size_t)NV * 256 * 2);
  ushort* h2bf = (ushort*)alloc((size_t)NV * 256 * 2);
  ushort* Wcat[3];
  for (int i = 0; i < 3; ++i)
    Wcat[i] = (ushort*)alloc((size_t)(2 * hc[i] + oc[i]) * ic[i] * 2);
  float*    easumA  = (float*)alloc(3 * 64);                  // 3 x 16 floats
  int*      countsA = (int*)alloc((size_t)3 * (NV + 1) * 4);  // adjacent for one memset
  int*      cursorA = (int*)alloc((size_t)3 * NV * 4);
  unsigned* csrA    = (unsigned*)alloc((size_t)3 * CSRN * 4);
  ushort*   eabA    = (ushort*)alloc((size_t)3 * CSRN * 16 * 2);  // reordered f16 ea

  // ---- single memset: easums + counts ----
  hipMemsetAsync(easumA, 0, 512 + (size_t)3 * (NV + 1) * 4, stream);

  // ---- batched prep: CSR hist + colsum (x3), weight casts, proj ----
  PrepArgs pa;
  for (int i = 0; i < 3; ++i) {
    pa.ei[i] = ei[i];
    pa.ea[i] = ea[i];
    pa.counts[i] = countsA + i * (NV + 1);
    pa.easum[i] = easumA + i * 16;
    pa.jobs[i * 3 + 0] = {in(11 + 11 * i), Wcat[i],                             ic[i], hc[i]};
    pa.jobs[i * 3 + 1] = {in(13 + 11 * i), Wcat[i] + (size_t)hc[i] * ic[i],     ic[i], hc[i]};
    pa.jobs[i * 3 + 2] = {in(20 + 11 * i), Wcat[i] + (size_t)2 * hc[i] * ic[i], ic[i], oc[i]};
  }
  pa.x = x; pa.Wp = in(7); pa.bp = in(8); pa.gp = in(9); pa.bep = in(10); pa.h0 = h0bf;
  prep_kernel<<<dim3(1344, 5), 256, 0, stream>>>(pa);

  // ---- batched scan + scatter (scatter also reorders ea -> f16 CSR order) ----
  scan_kernel<<<3, 1024, 0, stream>>>(countsA, cursorA);
  ScatArgs sa;
  for (int i = 0; i < 3; ++i) {
    sa.ei[i] = ei[i];
    sa.ea[i] = ea[i];
    sa.cursor[i] = cursorA + i * NV;
    sa.csr[i] = csrA + (size_t)i * CSRN;
    sa.eab[i] = eabA + (size_t)i * CSRN * 16;
    sa.HC[i] = hc[i];
  }
  scatter_kernel<<<dim3((NE + CSR_PAD + 255) / 256, 3), 256, 0, stream>>>(sa);

  // ---- per-layer: fused GEMM + fused aggregate ----
  const ushort* hin[3] = {h0bf, h1bf, h2bf};
  ushort* hout_bf[3] = {h1bf, h2bf, nullptr};
  for (int i = 0; i < 3; ++i) {
    int K = ic[i], HCm = hc[i], OC = oc[i];
    int Mtot = 2 * HCm + OC;
    gemm_fused<<<dim3(Mtot / 64, (NV + 127) / 128), 256, 0, stream>>>(
        hin[i], Wcat[i], in(12 + 11 * i), in(14 + 11 * i), in(21 + 11 * i),
        B1, B2, B3, NV, K, HCm, 2 * HCm, Mtot);
    const int* offs = countsA + i * (NV + 1);
    const unsigned* csr = csrA + (size_t)i * CSRN;
    const ushort* eab = eabA + (size_t)i * CSRN * 16;
    const float* easum = easumA + i * 16;
    if (i < 2) {
      fused_agg_kernel<4><<<NV, 256, 0, stream>>>(
          eab, easum, in(15 + 11 * i), B1, B2, in(16 + 11 * i),
          in(17 + 11 * i), in(18 + 11 * i), in(19 + 11 * i), B3,
          offs, csr, nullptr, hout_bf[i], NE);
    } else {
      fused_agg_kernel<1><<<(NV + 3) / 4, 256, 0, stream>>>(
          eab, easum, in(15 + 11 * i), B1, B2, in(16 + 11 * i),
          in(17 + 11 * i), in(18 + 11 * i), in(19 + 11 * i), B3,
          offs, csr, (float*)d_out, nullptr, NE);
    }
  }
}